// Round 1
// baseline (301.095 us; speedup 1.0000x reference)
//
#include <hip/hip_runtime.h>
#include <hip/hip_bf16.h>

// Problem constants (fixed by the reference's setup_inputs)
#define BB 2
#define CC 256      // channels per level
#define HH 100
#define WW 100
#define NN 256      // rois per batch
#define KK (BB*NN)  // 512 total rois
#define C3 (3*CC)   // 768 fused channels
#define OUTB 7
#define SR 2
#define NSAMP (OUTB*SR)   // 14 sample positions per axis
#define BINS (OUTB*OUTB)  // 49

// Value of the fused (concat of x0, 2x-upsampled x1, 4x-upsampled x2) feature
// at (b, y, x, c).  Upsample matches jax.image.resize 'bilinear':
// src coord = (i+0.5)/scale - 0.5, edge-clamped (JAX weight renorm == clamp).
__device__ __forceinline__ float feat_val(const float* __restrict__ x0,
                                          const float* __restrict__ x1,
                                          const float* __restrict__ x2,
                                          int b, int y, int x, int c) {
    if (c < CC) {
        return x0[(((size_t)b*CC + c)*HH + y)*WW + x];
    }
    const float* src;
    int L;        // source spatial size
    float s, t;   // coord = i*s - t
    int cl;
    if (c < 2*CC) { src = x1; L = 50; s = 0.5f;  t = 0.25f;  cl = c - CC; }
    else          { src = x2; L = 25; s = 0.25f; t = 0.375f; cl = c - 2*CC; }
    float cy = fminf(fmaxf((float)y * s - t, 0.0f), (float)(L - 1));
    float cx = fminf(fmaxf((float)x * s - t, 0.0f), (float)(L - 1));
    int yl = (int)cy, xl = (int)cx;          // floor (coords >= 0)
    int yh = min(yl + 1, L - 1), xh = min(xl + 1, L - 1);
    float fy = cy - (float)yl, fx = cx - (float)xl;
    const float* p = src + (((size_t)b*CC + cl)*L)*L;
    float v00 = p[yl*L + xl], v01 = p[yl*L + xh];
    float v10 = p[yh*L + xl], v11 = p[yh*L + xh];
    float hy = 1.0f - fy, hx = 1.0f - fx;
    return v00*(hy*hx) + v01*(hy*fx) + v10*(fy*hx) + v11*(fy*fx);
}

// Build fused feature F with channel-last layout: F[b][y][x][c], c in [0,768)
__global__ __launch_bounds__(256) void build_F(const float* __restrict__ x0,
                                               const float* __restrict__ x1,
                                               const float* __restrict__ x2,
                                               float* __restrict__ F) {
    int pos = blockIdx.x;              // 0 .. 2*100*100-1
    int b = pos / (HH*WW);
    int rem = pos - b*(HH*WW);
    int y = rem / WW;
    int x = rem - y*WW;
    int tid = threadIdx.x;
    float* dst = F + (size_t)pos * C3;
    dst[tid]        = feat_val(x0, x1, x2, b, y, x, tid);
    dst[CC + tid]   = feat_val(x0, x1, x2, b, y, x, CC + tid);
    dst[2*CC + tid] = feat_val(x0, x1, x2, b, y, x, 2*CC + tid);
}

template <bool STAGED>
__global__ __launch_bounds__(256) void roi_kernel(const float* __restrict__ F,
                                                  const float* __restrict__ x0,
                                                  const float* __restrict__ x1,
                                                  const float* __restrict__ x2,
                                                  const float* __restrict__ boxes,
                                                  const float* __restrict__ ratio_hw,
                                                  const float* __restrict__ offset_tl,
                                                  float* __restrict__ out) {
    __shared__ float tile[256 * BINS];       // 50176 B, layout [c_local][bin]
    __shared__ int   s_ylo[NSAMP], s_yhi[NSAMP], s_xlo[NSAMP], s_xhi[NSAMP];
    __shared__ float s_fy[NSAMP], s_fx[NSAMP];
    __shared__ int   s_vy[NSAMP], s_vx[NSAMP];

    const int tid = threadIdx.x;
    const int k = blockIdx.x;                // roi index 0..511
    const int chunk = blockIdx.y;            // channel chunk 0..2
    const int b = k >> 8;                    // N=256

    if (tid < 2*NSAMP) {
        // per-roi scalar setup (broadcast loads)
        float r0 = ratio_hw[0], o0 = offset_tl[0];
        float scale = (float)HH / (1250.0f * r0 + 2.0f * o0);
        float rH  = ratio_hw[2*b],  rW   = ratio_hw[2*b + 1];
        float top = offset_tl[2*b], left = offset_tl[2*b + 1];
        const float* bx = boxes + (size_t)k * 4;
        bool isx = (tid >= NSAMP);
        int i = isx ? tid - NSAMP : tid;
        float a, e;
        if (isx) { a = (bx[0]*rW + left)*scale; e = (bx[2]*rW + left)*scale; }
        else     { a = (bx[1]*rH + top)*scale;  e = (bx[3]*rH + top)*scale;  }
        float len = fmaxf(e - a, 1.0f);       // ALIGNED=False
        float bs = len * (1.0f / (float)OUTB);
        float g = (float)(i >> 1) + 0.25f + 0.5f * (float)(i & 1);
        float p = a + g * bs;
        int v = (p >= -1.0f && p <= (float)HH) ? 1 : 0;
        float cc = fminf(fmaxf(p, 0.0f), (float)(HH - 1));
        int lo = (int)floorf(cc);
        int hi = min(lo + 1, HH - 1);
        float fr = cc - (float)lo;
        if (isx) { s_xlo[i] = lo; s_xhi[i] = hi; s_fx[i] = fr; s_vx[i] = v; }
        else     { s_ylo[i] = lo; s_yhi[i] = hi; s_fy[i] = fr; s_vy[i] = v; }
    }
    __syncthreads();

    const int c = chunk * 256 + tid;
    const float* Fb = nullptr;
    if (STAGED) Fb = F + (size_t)b * (HH*WW) * C3 + c;

    for (int oy = 0; oy < OUTB; ++oy) {
        for (int ox = 0; ox < OUTB; ++ox) {
            float acc = 0.0f;
            #pragma unroll
            for (int sy = 0; sy < SR; ++sy) {
                const int iy = oy*SR + sy;
                const int yl = s_ylo[iy], yh = s_yhi[iy];
                const float fy = s_fy[iy];
                const int vy = s_vy[iy];
                #pragma unroll
                for (int sx = 0; sx < SR; ++sx) {
                    const int ix = ox*SR + sx;
                    if (vy && s_vx[ix]) {
                        const int xl = s_xlo[ix], xh = s_xhi[ix];
                        const float fx = s_fx[ix];
                        const float hy = 1.0f - fy, hx = 1.0f - fx;
                        float v00, v01, v10, v11;
                        if (STAGED) {
                            v00 = Fb[((size_t)yl*WW + xl) * C3];
                            v01 = Fb[((size_t)yl*WW + xh) * C3];
                            v10 = Fb[((size_t)yh*WW + xl) * C3];
                            v11 = Fb[((size_t)yh*WW + xh) * C3];
                        } else {
                            v00 = feat_val(x0, x1, x2, b, yl, xl, c);
                            v01 = feat_val(x0, x1, x2, b, yl, xh, c);
                            v10 = feat_val(x0, x1, x2, b, yh, xl, c);
                            v11 = feat_val(x0, x1, x2, b, yh, xh, c);
                        }
                        acc += v00*(hy*hx) + v01*(hy*fx) + v10*(fy*hx) + v11*(fy*fx);
                    }
                }
            }
            tile[tid * BINS + oy*OUTB + ox] = acc * 0.25f;
        }
    }
    __syncthreads();

    // Coalesced write: tile flat layout [c_local][bin] == out layout slice
    float* dst = out + (size_t)k * (C3*BINS) + (size_t)chunk * 256 * BINS;
    #pragma unroll
    for (int i = tid; i < 256 * BINS; i += 256) {
        dst[i] = tile[i];
    }
}

extern "C" void kernel_launch(void* const* d_in, const int* in_sizes, int n_in,
                              void* d_out, int out_size, void* d_ws, size_t ws_size,
                              hipStream_t stream) {
    const float* x0       = (const float*)d_in[0];
    const float* x1       = (const float*)d_in[1];
    const float* x2       = (const float*)d_in[2];
    const float* boxes    = (const float*)d_in[3];
    const float* ratio_hw = (const float*)d_in[4];
    const float* off_tl   = (const float*)d_in[5];
    float* out = (float*)d_out;

    const size_t needF = (size_t)BB * HH * WW * C3 * sizeof(float);  // 61.44 MB
    if (ws_size >= needF) {
        float* F = (float*)d_ws;
        build_F<<<dim3(BB*HH*WW), 256, 0, stream>>>(x0, x1, x2, F);
        roi_kernel<true><<<dim3(KK, 3), 256, 0, stream>>>(F, x0, x1, x2,
                                                          boxes, ratio_hw, off_tl, out);
    } else {
        roi_kernel<false><<<dim3(KK, 3), 256, 0, stream>>>(nullptr, x0, x1, x2,
                                                           boxes, ratio_hw, off_tl, out);
    }
}